// Round 2
// baseline (108.871 us; speedup 1.0000x reference)
//
#include <hip/hip_runtime.h>
#include <math.h>

#define H_IN  1024
#define W_IN  1024
#define HW_IN (H_IN * W_IN)
#define H_OUT 768
#define W_OUT 768
#define HW_OUT (H_OUT * W_OUT)

// LDS staging geometry
#define ST    40              // row stride in floats (multiple of 4; 8-bank stagger per row)
#define SROWS 32
#define SCOLS 36              // staged cols (x0 aligned down to 4)
#define PLANE (SROWS * ST)    // 1280 floats per plane

struct KC {
    float sig1, inv, slope, two_over_c, half_c, quarter_c, half_over_sig1;
    float a2, a0, m_in_root;
};

__device__ __forceinline__ float inv_sigmoid(float q, const KC k) {
    if (q <= 0.f) return q * k.inv;
    if (q >= 1.f) return q * k.inv + (1.f - k.inv);
    float ssq = 2.f * k.sig1 * q - k.sig1;
    ssq = fminf(fmaxf(ssq, -0.999999f), 0.999999f);
    return k.two_over_c * atanhf(ssq) + 0.5f;
}

__device__ __forceinline__ float ext_sigmoid(float q, const KC k) {
    if (q <= 0.f) return k.slope * q;
    if (q >= 1.f) return k.slope * q + (1.f - k.slope);
    return k.half_over_sig1 * tanhf(k.half_c * q - k.quarter_c) + 0.5f;
}

__device__ __forceinline__ float mitchell(float xv) {
    float ax = fabsf(xv);
    if (ax >= 2.f) return 0.f;
    float ax2 = ax * ax, ax3 = ax2 * ax;
    if (ax < 1.f) return 7.f / 6.f * ax3 - 2.f * ax2 + 8.f / 9.f;
    return -7.f / 18.f * ax3 + 2.f * ax2 - 10.f / 3.f * ax + 16.f / 9.f;
}

__device__ __forceinline__ float robidoux(float r2, const KC k) {
    if (r2 >= 4.f) return 0.f;
    float r = sqrtf(r2 + 1e-8f);
    if (r2 < 1.f) return r2 * (-3.f * r + k.a2) + k.a0;
    float t = r - 2.f;
    return (r + k.m_in_root) * t * t;
}

__global__ __launch_bounds__(256)
void sig_precompute(const float4* __restrict__ img, float4* __restrict__ sig,
                    int n4, KC k) {
    int i = blockIdx.x * 256 + threadIdx.x;
    if (i >= n4) return;
    float4 v = img[i];
    float4 r;
    r.x = inv_sigmoid(v.x, k);
    r.y = inv_sigmoid(v.y, k);
    r.z = inv_sigmoid(v.z, k);
    r.w = inv_sigmoid(v.w, k);
    sig[i] = r;
}

template <bool PRE>
__global__ __launch_bounds__(256)
void lohalo_main(const float* __restrict__ img, const float* __restrict__ sig,
                 const float* __restrict__ grid, float* __restrict__ out, KC k) {
    __shared__ float sm[6 * PLANE];   // img0,1,2, sig0,1,2  (30 KB)
    __shared__ int sred[16];

    const int tid = threadIdx.x;
    const int lx = tid & 15, ly = tid >> 4;
    const int x = blockIdx.x * 16 + lx;
    const int y = blockIdx.y * 16 + ly;
    const int pix = y * W_OUT + x;

    // ---- Jacobian via central differences with edge clamping ----
    const float2* G = (const float2*)grid;
    float2 gc  = G[pix];
    float2 gxm = G[y * W_OUT + max(x - 1, 0)];
    float2 gxp = G[y * W_OUT + min(x + 1, W_OUT - 1)];
    float2 gym = G[max(y - 1, 0) * W_OUT + x];
    float2 gyp = G[min(y + 1, H_OUT - 1) * W_OUT + x];
    float J00 = (gxp.x - gxm.x) * 0.5f, J10 = (gxp.y - gxm.y) * 0.5f;
    float J01 = (gyp.x - gym.x) * 0.5f, J11 = (gyp.y - gym.y) * 0.5f;
    float det = J00 * J11 - J01 * J10 + 1e-8f;
    float a  = J11 / det, b = -J01 / det;
    float cI = -J10 / det, d = J00 / det;
    float n11 = a * a + b * b, n12 = a * cI + b * d, n22 = cI * cI + d * d;
    float frob = n11 + n22;
    float disc = frob * frob - 4.f / (det * det);
    float sdisc = sqrtf(fmaxf(disc, 0.f));
    float twice = frob + sdisc;
    float s1s1 = 0.5f * twice, s2s2 = 0.5f * (frob - sdisc);
    float major = sqrtf(fmaxf(s1s1, 1.f));
    float minr  = sqrtf(fmaxf(s2s2, 1.f));
    float diff1 = s1s1 - n11, diff2 = s1s1 - n22;
    bool  cnd  = diff1 * diff1 >= diff2 * diff2;
    float tu11 = cnd ? n12 : diff2;
    float tu21 = cnd ? diff1 : n12;
    float nrm = sqrtf(tu11 * tu11 + tu21 * tu21);
    float u11 = nrm > 0.f ? tu11 / nrm : 1.f;
    float u21 = nrm > 0.f ? tu21 / nrm : 0.f;
    float cMx = u11 / major, cMy = u21 / major;
    float cmx = -u21 / minr, cmy = u11 / minr;
    float theta = 1.f / (major * minr);
    bool need_ewa = twice > 2.f;

    // ---- window base ----
    float fix = floorf(gc.x), fiy = floorf(gc.y);
    int ix = (int)fix, iy = (int)fiy;
    float fx = gc.x - (fix + 0.5f);
    float fy = gc.y - (fiy + 0.5f);

    // ---- block bounding box (wave shfl reduce + LDS combine) ----
    int mnx = ix, mxx = ix, mny = iy, mxy = iy;
#pragma unroll
    for (int m = 1; m < 64; m <<= 1) {
        mnx = min(mnx, __shfl_xor(mnx, m));
        mxx = max(mxx, __shfl_xor(mxx, m));
        mny = min(mny, __shfl_xor(mny, m));
        mxy = max(mxy, __shfl_xor(mxy, m));
    }
    const int wid = tid >> 6;
    if ((tid & 63) == 0) {
        sred[wid * 4 + 0] = mnx;
        sred[wid * 4 + 1] = mxx;
        sred[wid * 4 + 2] = mny;
        sred[wid * 4 + 3] = mxy;
    }
    __syncthreads();
    mnx = min(min(sred[0], sred[4]),  min(sred[8],  sred[12]));
    mxx = max(max(sred[1], sred[5]),  max(sred[9],  sred[13]));
    mny = min(min(sred[2], sred[6]),  min(sred[10], sred[14]));
    mxy = max(max(sred[3], sred[7]),  max(sred[11], sred[15]));

    const int x0 = (mnx - 2) & ~3;    // 16B-aligned staging origin
    const int y0 = mny - 2;
    const bool fits = (mxx + 3 - x0 < SCOLS) && (mxy + 3 - y0 < SROWS);

    float mx_[6], my_[6];
    float qx1[6], qx2[6], qy1[6], qy2[6];
    int cxi[6], cyi[6];
#pragma unroll
    for (int t = 0; t < 6; t++) {
        float o = (float)(t - 2);
        float rx = fx - o, ry = fy - o;
        mx_[t] = mitchell(rx);
        my_[t] = mitchell(ry);
        qx1[t] = rx * cMx;
        qx2[t] = rx * cmx;
        qy1[t] = ry * cMy;
        qy2[t] = ry * cmy;
        cxi[t] = min(max(ix + (t - 2), 0), W_IN - 1);
        cyi[t] = min(max(iy + (t - 2), 0), H_IN - 1);
    }

    float ms0 = 0.f, ms1 = 0.f, ms2 = 0.f;
    bool any_ewa = __any(need_ewa);

    if (fits) {
        // ---- cooperative staging into LDS ----
        const bool xfast = (x0 >= 0) && (x0 + SCOLS <= W_IN);
        if (xfast) {
            for (int i = tid; i < 6 * SROWS * 9; i += 256) {
                int p   = i / 288;
                int rem = i - p * 288;
                int r   = rem / 9;
                int q   = rem - r * 9;
                int gr  = min(max(y0 + r, 0), H_IN - 1);
                int ga  = gr * W_IN + x0 + q * 4;
                float4 v;
                if (p < 3) {
                    v = *(const float4*)&img[p * HW_IN + ga];
                } else if (PRE) {
                    v = *(const float4*)&sig[(p - 3) * HW_IN + ga];
                } else {
                    float4 t = *(const float4*)&img[(p - 3) * HW_IN + ga];
                    v.x = inv_sigmoid(t.x, k);
                    v.y = inv_sigmoid(t.y, k);
                    v.z = inv_sigmoid(t.z, k);
                    v.w = inv_sigmoid(t.w, k);
                }
                *(float4*)&sm[p * PLANE + r * ST + q * 4] = v;
            }
        } else {
            for (int i = tid; i < 6 * SROWS * SCOLS; i += 256) {
                int p   = i / (SROWS * SCOLS);
                int rem = i - p * (SROWS * SCOLS);
                int r   = rem / SCOLS;
                int c   = rem - r * SCOLS;
                int gr  = min(max(y0 + r, 0), H_IN - 1);
                int gcc = min(max(x0 + c, 0), W_IN - 1);
                int ga  = gr * W_IN + gcc;
                float v;
                if (p < 3) v = img[p * HW_IN + ga];
                else if (PRE) v = sig[(p - 3) * HW_IN + ga];
                else v = inv_sigmoid(img[(p - 3) * HW_IN + ga], k);
                sm[p * PLANE + r * ST + c] = v;
            }
        }
        __syncthreads();

        // LDS-relative tap coords (proven in-range given fits)
        int lxo[6], lyo[6];
#pragma unroll
        for (int t = 0; t < 6; t++) {
            lxo[t] = cxi[t] - x0;
            lyo[t] = (cyi[t] - y0) * ST;
        }

        if (any_ewa) {
            float es0 = 0.f, es1 = 0.f, es2 = 0.f, tw = 0.f;
#pragma unroll
            for (int ty = 0; ty < 6; ty++) {
                const int rb = lyo[ty];
                const float wmy = my_[ty];
                const float qy1v = qy1[ty], qy2v = qy2[ty];
#pragma unroll
                for (int tx = 0; tx < 6; tx++) {
                    const int o = rb + lxo[tx];
                    float p0 = sm[o];
                    float p1 = sm[PLANE + o];
                    float p2 = sm[2 * PLANE + o];
                    float s0 = sm[3 * PLANE + o];
                    float s1 = sm[4 * PLANE + o];
                    float s2 = sm[5 * PLANE + o];
                    float wm = mx_[tx] * wmy;
                    ms0 = fmaf(s0, wm, ms0);
                    ms1 = fmaf(s1, wm, ms1);
                    ms2 = fmaf(s2, wm, ms2);
                    float q1 = qx1[tx] + qy1v;
                    float q2 = qx2[tx] + qy2v;
                    float r2 = q1 * q1 + q2 * q2;
                    float we = robidoux(r2, k);
                    tw += we;
                    es0 = fmaf(p0, we, es0);
                    es1 = fmaf(p1, we, es1);
                    es2 = fmaf(p2, we, es2);
                }
            }
            tw += 1e-8f;
            float mv0 = ext_sigmoid(ms0, k);
            float mv1 = ext_sigmoid(ms1, k);
            float mv2 = ext_sigmoid(ms2, k);
            float ev0 = es0 / tw, ev1 = es1 / tw, ev2 = es2 / tw;
            float om = 1.f - theta;
            out[pix]              = need_ewa ? theta * mv0 + om * ev0 : mv0;
            out[HW_OUT + pix]     = need_ewa ? theta * mv1 + om * ev1 : mv1;
            out[2 * HW_OUT + pix] = need_ewa ? theta * mv2 + om * ev2 : mv2;
        } else {
#pragma unroll
            for (int ty = 0; ty < 6; ty++) {
                const int rb = lyo[ty];
                const float wmy = my_[ty];
#pragma unroll
                for (int tx = 0; tx < 6; tx++) {
                    const int o = rb + lxo[tx];
                    float wm = mx_[tx] * wmy;
                    ms0 = fmaf(sm[3 * PLANE + o], wm, ms0);
                    ms1 = fmaf(sm[4 * PLANE + o], wm, ms1);
                    ms2 = fmaf(sm[5 * PLANE + o], wm, ms2);
                }
            }
            out[pix]              = ext_sigmoid(ms0, k);
            out[HW_OUT + pix]     = ext_sigmoid(ms1, k);
            out[2 * HW_OUT + pix] = ext_sigmoid(ms2, k);
        }
    } else {
        // ---- fallback: per-thread global gather (rare; bbox too large) ----
        if (any_ewa) {
            float es0 = 0.f, es1 = 0.f, es2 = 0.f, tw = 0.f;
#pragma unroll
            for (int ty = 0; ty < 6; ty++) {
                const int rb = cyi[ty] * W_IN;
                const float wmy = my_[ty];
#pragma unroll
                for (int tx = 0; tx < 6; tx++) {
                    const int off = rb + cxi[tx];
                    float p0 = img[off];
                    float p1 = img[off + HW_IN];
                    float p2 = img[off + 2 * HW_IN];
                    float s0, s1, s2;
                    if constexpr (PRE) {
                        s0 = sig[off];
                        s1 = sig[off + HW_IN];
                        s2 = sig[off + 2 * HW_IN];
                    } else {
                        s0 = inv_sigmoid(p0, k);
                        s1 = inv_sigmoid(p1, k);
                        s2 = inv_sigmoid(p2, k);
                    }
                    float wm = mx_[tx] * wmy;
                    ms0 = fmaf(s0, wm, ms0);
                    ms1 = fmaf(s1, wm, ms1);
                    ms2 = fmaf(s2, wm, ms2);
                    float q1 = qx1[tx] + qy1[ty];
                    float q2 = qx2[tx] + qy2[ty];
                    float r2 = q1 * q1 + q2 * q2;
                    float we = robidoux(r2, k);
                    tw += we;
                    es0 = fmaf(p0, we, es0);
                    es1 = fmaf(p1, we, es1);
                    es2 = fmaf(p2, we, es2);
                }
            }
            tw += 1e-8f;
            float mv0 = ext_sigmoid(ms0, k);
            float mv1 = ext_sigmoid(ms1, k);
            float mv2 = ext_sigmoid(ms2, k);
            float ev0 = es0 / tw, ev1 = es1 / tw, ev2 = es2 / tw;
            float om = 1.f - theta;
            out[pix]              = need_ewa ? theta * mv0 + om * ev0 : mv0;
            out[HW_OUT + pix]     = need_ewa ? theta * mv1 + om * ev1 : mv1;
            out[2 * HW_OUT + pix] = need_ewa ? theta * mv2 + om * ev2 : mv2;
        } else {
#pragma unroll
            for (int ty = 0; ty < 6; ty++) {
                const int rb = cyi[ty] * W_IN;
                const float wmy = my_[ty];
#pragma unroll
                for (int tx = 0; tx < 6; tx++) {
                    const int off = rb + cxi[tx];
                    float s0, s1, s2;
                    if constexpr (PRE) {
                        s0 = sig[off];
                        s1 = sig[off + HW_IN];
                        s2 = sig[off + 2 * HW_IN];
                    } else {
                        s0 = inv_sigmoid(img[off], k);
                        s1 = inv_sigmoid(img[off + HW_IN], k);
                        s2 = inv_sigmoid(img[off + 2 * HW_IN], k);
                    }
                    float wm = mx_[tx] * wmy;
                    ms0 = fmaf(s0, wm, ms0);
                    ms1 = fmaf(s1, wm, ms1);
                    ms2 = fmaf(s2, wm, ms2);
                }
            }
            out[pix]              = ext_sigmoid(ms0, k);
            out[HW_OUT + pix]     = ext_sigmoid(ms1, k);
            out[2 * HW_OUT + pix] = ext_sigmoid(ms2, k);
        }
    }
}

extern "C" void kernel_launch(void* const* d_in, const int* in_sizes, int n_in,
                              void* d_out, int out_size, void* d_ws, size_t ws_size,
                              hipStream_t stream) {
    const float* img  = (const float*)d_in[0];
    const float* grid = (const float*)d_in[1];
    float* out = (float*)d_out;

    KC k;
    const double cc = 3.38589;
    const double s1 = tanh(0.25 * cc);
    const double slope = (1.0 / s1 - s1) * 0.25 * cc;
    k.sig1 = (float)s1;
    k.slope = (float)slope;
    k.inv = (float)(1.0 / slope);
    k.two_over_c = (float)(2.0 / cc);
    k.half_c = (float)(0.5 * cc);
    k.quarter_c = (float)(0.25 * cc);
    k.half_over_sig1 = (float)(0.5 / s1);
    const double sq2 = sqrt(2.0);
    k.a2 = (float)((45739.0 + 7164.0 * sq2) / 10319.0);
    k.a0 = (float)((-8926.0 - 14328.0 * sq2) / 10319.0);
    k.m_in_root = (float)((-103.0 - 36.0 * sq2) / (7.0 + 72.0 * sq2));

    dim3 grd(W_OUT / 16, H_OUT / 16);
    const size_t sig_bytes = (size_t)3 * HW_IN * sizeof(float);

    if (ws_size >= sig_bytes) {
        float* sig = (float*)d_ws;
        int n4 = 3 * HW_IN / 4;
        sig_precompute<<<(n4 + 255) / 256, 256, 0, stream>>>(
            (const float4*)img, (float4*)sig, n4, k);
        lohalo_main<true><<<grd, 256, 0, stream>>>(img, sig, grid, out, k);
    } else {
        lohalo_main<false><<<grd, 256, 0, stream>>>(img, nullptr, grid, out, k);
    }
}

// Round 3
// 88.581 us; speedup vs baseline: 1.2291x; 1.2291x over previous
//
#include <hip/hip_runtime.h>
#include <math.h>

#define H_IN  1024
#define W_IN  1024
#define HW_IN (H_IN * W_IN)
#define H_OUT 768
#define W_OUT 768
#define HW_OUT (H_OUT * W_OUT)

struct KC {
    float sig1, inv, slope, two_over_c, half_c, quarter_c, half_over_sig1;
    float a2, a0, m_in_root;
};

__device__ __forceinline__ float inv_sigmoid(float q, const KC k) {
    if (q <= 0.f) return q * k.inv;
    if (q >= 1.f) return q * k.inv + (1.f - k.inv);
    float ssq = 2.f * k.sig1 * q - k.sig1;
    ssq = fminf(fmaxf(ssq, -0.999999f), 0.999999f);
    return k.two_over_c * atanhf(ssq) + 0.5f;
}

__device__ __forceinline__ float ext_sigmoid(float q, const KC k) {
    if (q <= 0.f) return k.slope * q;
    if (q >= 1.f) return k.slope * q + (1.f - k.slope);
    return k.half_over_sig1 * tanhf(k.half_c * q - k.quarter_c) + 0.5f;
}

__device__ __forceinline__ float mitchell(float xv) {
    float ax = fabsf(xv);
    if (ax >= 2.f) return 0.f;
    float ax2 = ax * ax, ax3 = ax2 * ax;
    if (ax < 1.f) return 7.f / 6.f * ax3 - 2.f * ax2 + 8.f / 9.f;
    return -7.f / 18.f * ax3 + 2.f * ax2 - 10.f / 3.f * ax + 16.f / 9.f;
}

__device__ __forceinline__ float robidoux(float r2, const KC k) {
    if (r2 >= 4.f) return 0.f;
    float r = sqrtf(r2 + 1e-8f);
    if (r2 < 1.f) return r2 * (-3.f * r + k.a2) + k.a0;
    float t = r - 2.f;
    return (r + k.m_in_root) * t * t;
}

// Pack [p0,s0,p1,s1,p2,s2] per pixel: kills the 4MB-strided L1 set aliasing
// and lets the window row be loaded as one contiguous float4 stream.
__global__ __launch_bounds__(256)
void pack_kernel(const float* __restrict__ img, float* __restrict__ packed, KC k) {
    int i = blockIdx.x * 256 + threadIdx.x;     // pixel-pair index
    if (i >= HW_IN / 2) return;
    int x2 = i * 2;
    float2 c0 = *(const float2*)&img[x2];
    float2 c1 = *(const float2*)&img[HW_IN + x2];
    float2 c2 = *(const float2*)&img[2 * HW_IN + x2];
    float4 o0 = make_float4(c0.x, inv_sigmoid(c0.x, k), c1.x, inv_sigmoid(c1.x, k));
    float4 o1 = make_float4(c2.x, inv_sigmoid(c2.x, k), c0.y, inv_sigmoid(c0.y, k));
    float4 o2 = make_float4(c1.y, inv_sigmoid(c1.y, k), c2.y, inv_sigmoid(c2.y, k));
    float4* o = (float4*)packed + (size_t)3 * i;
    o[0] = o0; o[1] = o1; o[2] = o2;
}

__global__ __launch_bounds__(256)
void lohalo_packed(const float* __restrict__ packed, const float* __restrict__ grid,
                   float* __restrict__ out, KC k) {
    const int tid = threadIdx.x;
    const int lx = tid & 15, ly = tid >> 4;
    const int x = blockIdx.x * 16 + lx;
    const int y = blockIdx.y * 16 + ly;
    const int pix = y * W_OUT + x;

    // ---- Jacobian ----
    const float2* G = (const float2*)grid;
    float2 gc  = G[pix];
    float2 gxm = G[y * W_OUT + max(x - 1, 0)];
    float2 gxp = G[y * W_OUT + min(x + 1, W_OUT - 1)];
    float2 gym = G[max(y - 1, 0) * W_OUT + x];
    float2 gyp = G[min(y + 1, H_OUT - 1) * W_OUT + x];
    float J00 = (gxp.x - gxm.x) * 0.5f, J10 = (gxp.y - gxm.y) * 0.5f;
    float J01 = (gyp.x - gym.x) * 0.5f, J11 = (gyp.y - gym.y) * 0.5f;
    float det = J00 * J11 - J01 * J10 + 1e-8f;
    float a  = J11 / det, b = -J01 / det;
    float cI = -J10 / det, d = J00 / det;
    float n11 = a * a + b * b, n12 = a * cI + b * d, n22 = cI * cI + d * d;
    float frob = n11 + n22;
    float disc = frob * frob - 4.f / (det * det);
    float sdisc = sqrtf(fmaxf(disc, 0.f));
    float twice = frob + sdisc;
    float s1s1 = 0.5f * twice, s2s2 = 0.5f * (frob - sdisc);
    float major = sqrtf(fmaxf(s1s1, 1.f));
    float minr  = sqrtf(fmaxf(s2s2, 1.f));
    float diff1 = s1s1 - n11, diff2 = s1s1 - n22;
    bool  cnd  = diff1 * diff1 >= diff2 * diff2;
    float tu11 = cnd ? n12 : diff2;
    float tu21 = cnd ? diff1 : n12;
    float nrm = sqrtf(tu11 * tu11 + tu21 * tu21);
    float u11 = nrm > 0.f ? tu11 / nrm : 1.f;
    float u21 = nrm > 0.f ? tu21 / nrm : 0.f;
    float cMx = u11 / major, cMy = u21 / major;
    float cmx = -u21 / minr, cmy = u11 / minr;
    float theta = 1.f / (major * minr);
    bool need_ewa = twice > 2.f;

    float fix = floorf(gc.x), fiy = floorf(gc.y);
    int ix = (int)fix, iy = (int)fiy;
    float fx = gc.x - (fix + 0.5f);
    float fy = gc.y - (fiy + 0.5f);

    // y-weights (shared by both paths)
    float my6[6], qya[6], qyb[6];
#pragma unroll
    for (int r = 0; r < 6; r++) {
        float rely = fy + (float)(2 - r);
        my6[r] = mitchell(rely);
        qya[r] = rely * cMy;
        qyb[r] = rely * cmy;
    }

    float ms0 = 0.f, ms1 = 0.f, ms2 = 0.f;
    float es0 = 0.f, es1 = 0.f, es2 = 0.f, tw = 0.f;

    const int x0 = (ix - 2) & ~1;
    const int s  = (ix - 2) - x0;                 // 0 or 1
    const bool interior = (x0 >= 0) && (x0 + 8 <= W_IN) && (iy >= 2) && (iy + 4 <= H_IN);

    if (__all(interior)) {
        // x-weights at the 7 even-aligned buffer positions
        float fxs = fx + (float)(s + 2);
        float mxv[7], qxa[7], qxb[7], em[7];
#pragma unroll
        for (int j = 0; j < 7; j++) {
            float relx = fxs - (float)j;
            mxv[j] = mitchell(relx);              // exact 0 outside window
            qxa[j] = relx * cMx;
            qxb[j] = relx * cmx;
            em[j]  = 1.f;
        }
        em[0] = (s == 0) ? 1.f : 0.f;             // EWA hard window mask
        em[6] = 1.f - em[0];

        const float* rowbase = packed + ((size_t)(iy - 2) * W_IN + x0) * 6;
#pragma unroll
        for (int r = 0; r < 6; r++) {
            const float4* p4 = (const float4*)(rowbase + (size_t)r * (W_IN * 6));
            float v[44];
#pragma unroll
            for (int jj = 0; jj < 11; jj++) {
                float4 t = p4[jj];
                v[4 * jj]     = t.x;
                v[4 * jj + 1] = t.y;
                v[4 * jj + 2] = t.z;
                v[4 * jj + 3] = t.w;
            }
            const float wmy = my6[r];
            const float qy1 = qya[r], qy2 = qyb[r];
#pragma unroll
            for (int j = 0; j < 7; j++) {
                float wm = mxv[j] * wmy;
                ms0 = fmaf(v[6 * j + 1], wm, ms0);
                ms1 = fmaf(v[6 * j + 3], wm, ms1);
                ms2 = fmaf(v[6 * j + 5], wm, ms2);
                float q1 = qxa[j] + qy1;
                float q2 = qxb[j] + qy2;
                float r2 = q1 * q1 + q2 * q2;
                float we = robidoux(r2, k) * em[j];
                tw += we;
                es0 = fmaf(v[6 * j],     we, es0);
                es1 = fmaf(v[6 * j + 2], we, es1);
                es2 = fmaf(v[6 * j + 4], we, es2);
            }
        }
    } else {
        // border path: clamped per-tap scalar gathers from packed
        float mtx[6], qxa6[6], qxb6[6];
        int cxi[6], cyi[6];
#pragma unroll
        for (int t = 0; t < 6; t++) {
            float relx = fx - (float)(t - 2);
            mtx[t] = mitchell(relx);
            qxa6[t] = relx * cMx;
            qxb6[t] = relx * cmx;
            cxi[t] = min(max(ix + (t - 2), 0), W_IN - 1);
            cyi[t] = min(max(iy + (t - 2), 0), H_IN - 1);
        }
#pragma unroll
        for (int ty = 0; ty < 6; ty++) {
            const int rb = cyi[ty] * W_IN;
            const float wmy = my6[ty];
            const float qy1 = qya[ty], qy2 = qyb[ty];
#pragma unroll
            for (int tx = 0; tx < 6; tx++) {
                const float* pp = packed + (size_t)(rb + cxi[tx]) * 6;
                float2 f0 = *(const float2*)(pp);
                float2 f1 = *(const float2*)(pp + 2);
                float2 f2 = *(const float2*)(pp + 4);
                float wm = mtx[tx] * wmy;
                ms0 = fmaf(f0.y, wm, ms0);
                ms1 = fmaf(f1.y, wm, ms1);
                ms2 = fmaf(f2.y, wm, ms2);
                float q1 = qxa6[tx] + qy1;
                float q2 = qxb6[tx] + qy2;
                float r2 = q1 * q1 + q2 * q2;
                float we = robidoux(r2, k);
                tw += we;
                es0 = fmaf(f0.x, we, es0);
                es1 = fmaf(f1.x, we, es1);
                es2 = fmaf(f2.x, we, es2);
            }
        }
    }

    tw += 1e-8f;
    float itw = 1.f / tw;
    float mv0 = ext_sigmoid(ms0, k);
    float mv1 = ext_sigmoid(ms1, k);
    float mv2 = ext_sigmoid(ms2, k);
    float om = 1.f - theta;
    out[pix]              = need_ewa ? theta * mv0 + om * (es0 * itw) : mv0;
    out[HW_OUT + pix]     = need_ewa ? theta * mv1 + om * (es1 * itw) : mv1;
    out[2 * HW_OUT + pix] = need_ewa ? theta * mv2 + om * (es2 * itw) : mv2;
}

// Fallback if ws is too small for the packed plane: direct global gather.
__global__ __launch_bounds__(256)
void lohalo_fallback(const float* __restrict__ img, const float* __restrict__ grid,
                     float* __restrict__ out, KC k) {
    const int tid = threadIdx.x;
    const int lx = tid & 15, ly = tid >> 4;
    const int x = blockIdx.x * 16 + lx;
    const int y = blockIdx.y * 16 + ly;
    const int pix = y * W_OUT + x;

    const float2* G = (const float2*)grid;
    float2 gc  = G[pix];
    float2 gxm = G[y * W_OUT + max(x - 1, 0)];
    float2 gxp = G[y * W_OUT + min(x + 1, W_OUT - 1)];
    float2 gym = G[max(y - 1, 0) * W_OUT + x];
    float2 gyp = G[min(y + 1, H_OUT - 1) * W_OUT + x];
    float J00 = (gxp.x - gxm.x) * 0.5f, J10 = (gxp.y - gxm.y) * 0.5f;
    float J01 = (gyp.x - gym.x) * 0.5f, J11 = (gyp.y - gym.y) * 0.5f;
    float det = J00 * J11 - J01 * J10 + 1e-8f;
    float a  = J11 / det, b = -J01 / det;
    float cI = -J10 / det, d = J00 / det;
    float n11 = a * a + b * b, n12 = a * cI + b * d, n22 = cI * cI + d * d;
    float frob = n11 + n22;
    float disc = frob * frob - 4.f / (det * det);
    float sdisc = sqrtf(fmaxf(disc, 0.f));
    float twice = frob + sdisc;
    float s1s1 = 0.5f * twice, s2s2 = 0.5f * (frob - sdisc);
    float major = sqrtf(fmaxf(s1s1, 1.f));
    float minr  = sqrtf(fmaxf(s2s2, 1.f));
    float diff1 = s1s1 - n11, diff2 = s1s1 - n22;
    bool  cnd  = diff1 * diff1 >= diff2 * diff2;
    float tu11 = cnd ? n12 : diff2;
    float tu21 = cnd ? diff1 : n12;
    float nrm = sqrtf(tu11 * tu11 + tu21 * tu21);
    float u11 = nrm > 0.f ? tu11 / nrm : 1.f;
    float u21 = nrm > 0.f ? tu21 / nrm : 0.f;
    float cMx = u11 / major, cMy = u21 / major;
    float cmx = -u21 / minr, cmy = u11 / minr;
    float theta = 1.f / (major * minr);
    bool need_ewa = twice > 2.f;

    float fix = floorf(gc.x), fiy = floorf(gc.y);
    int ix = (int)fix, iy = (int)fiy;
    float fx = gc.x - (fix + 0.5f);
    float fy = gc.y - (fiy + 0.5f);

    float mtx[6], mty[6], qxa6[6], qxb6[6], qya6[6], qyb6[6];
    int cxi[6], cyi[6];
#pragma unroll
    for (int t = 0; t < 6; t++) {
        float relx = fx - (float)(t - 2);
        float rely = fy - (float)(t - 2);
        mtx[t] = mitchell(relx);
        mty[t] = mitchell(rely);
        qxa6[t] = relx * cMx; qxb6[t] = relx * cmx;
        qya6[t] = rely * cMy; qyb6[t] = rely * cmy;
        cxi[t] = min(max(ix + (t - 2), 0), W_IN - 1);
        cyi[t] = min(max(iy + (t - 2), 0), H_IN - 1);
    }
    float ms0 = 0.f, ms1 = 0.f, ms2 = 0.f;
    float es0 = 0.f, es1 = 0.f, es2 = 0.f, tw = 0.f;
#pragma unroll
    for (int ty = 0; ty < 6; ty++) {
        const int rb = cyi[ty] * W_IN;
        const float wmy = mty[ty];
#pragma unroll
        for (int tx = 0; tx < 6; tx++) {
            const int off = rb + cxi[tx];
            float p0 = img[off];
            float p1 = img[off + HW_IN];
            float p2 = img[off + 2 * HW_IN];
            float s0 = inv_sigmoid(p0, k);
            float s1 = inv_sigmoid(p1, k);
            float s2 = inv_sigmoid(p2, k);
            float wm = mtx[tx] * wmy;
            ms0 = fmaf(s0, wm, ms0);
            ms1 = fmaf(s1, wm, ms1);
            ms2 = fmaf(s2, wm, ms2);
            float q1 = qxa6[tx] + qya6[ty];
            float q2 = qxb6[tx] + qyb6[ty];
            float r2 = q1 * q1 + q2 * q2;
            float we = robidoux(r2, k);
            tw += we;
            es0 = fmaf(p0, we, es0);
            es1 = fmaf(p1, we, es1);
            es2 = fmaf(p2, we, es2);
        }
    }
    tw += 1e-8f;
    float itw = 1.f / tw;
    float mv0 = ext_sigmoid(ms0, k);
    float mv1 = ext_sigmoid(ms1, k);
    float mv2 = ext_sigmoid(ms2, k);
    float om = 1.f - theta;
    out[pix]              = need_ewa ? theta * mv0 + om * (es0 * itw) : mv0;
    out[HW_OUT + pix]     = need_ewa ? theta * mv1 + om * (es1 * itw) : mv1;
    out[2 * HW_OUT + pix] = need_ewa ? theta * mv2 + om * (es2 * itw) : mv2;
}

extern "C" void kernel_launch(void* const* d_in, const int* in_sizes, int n_in,
                              void* d_out, int out_size, void* d_ws, size_t ws_size,
                              hipStream_t stream) {
    const float* img  = (const float*)d_in[0];
    const float* grid = (const float*)d_in[1];
    float* out = (float*)d_out;

    KC k;
    const double cc = 3.38589;
    const double s1 = tanh(0.25 * cc);
    const double slope = (1.0 / s1 - s1) * 0.25 * cc;
    k.sig1 = (float)s1;
    k.slope = (float)slope;
    k.inv = (float)(1.0 / slope);
    k.two_over_c = (float)(2.0 / cc);
    k.half_c = (float)(0.5 * cc);
    k.quarter_c = (float)(0.25 * cc);
    k.half_over_sig1 = (float)(0.5 / s1);
    const double sq2 = sqrt(2.0);
    k.a2 = (float)((45739.0 + 7164.0 * sq2) / 10319.0);
    k.a0 = (float)((-8926.0 - 14328.0 * sq2) / 10319.0);
    k.m_in_root = (float)((-103.0 - 36.0 * sq2) / (7.0 + 72.0 * sq2));

    dim3 grd(W_OUT / 16, H_OUT / 16);
    const size_t packed_bytes = (size_t)HW_IN * 6 * sizeof(float);   // 24 MB

    if (ws_size >= packed_bytes) {
        float* packed = (float*)d_ws;
        int npairs = HW_IN / 2;
        pack_kernel<<<(npairs + 255) / 256, 256, 0, stream>>>(img, packed, k);
        lohalo_packed<<<grd, 256, 0, stream>>>(packed, grid, out, k);
    } else {
        lohalo_fallback<<<grd, 256, 0, stream>>>(img, grid, out, k);
    }
}